// Round 5
// baseline (24.594 us; speedup 1.0000x reference)
//
#include <hip/hip_runtime.h>
#include <math.h>

#define NG 1024
#define IH 256
#define IW 256
#define NPIX (IH*IW)

// sorted layout:
//   cull[r]   = float4 (u, v, rx, ry)                 -- coalesced cull reads
//   recs[2r]  = float4 (0.5*conA, conB, 0.5*conC, smax)
//   recs[2r+1]= float4 (op, cr, cg, cb)

// ---------------- Kernel 1: pre + block-local global rank + scatter ----------------
// 16 blocks x 256 threads. Block b owns gaussians [b*64, b*64+64).
//  step 1: all 256 threads compute zc for ALL 1024 gaussians -> LDS zall (cheap).
//  step 2: wave 0 does the heavy per-gaussian pre (regs only)  ||  waves 1-3
//          compute 4 quarter partial rank counts for the block's 64 gaussians.
//  step 3: thread t<64 sums partials -> stable global rank r, scatters record.
__global__ __launch_bounds__(256) void k_pre(
    const float* __restrict__ means, const float* __restrict__ scales,
    const float* __restrict__ quats, const float* __restrict__ opacs,
    const float* __restrict__ sh0, const float* __restrict__ shn,
    const float* __restrict__ times, const float* __restrict__ durs,
    const float* __restrict__ vels, const float* __restrict__ tptr,
    const float* __restrict__ w2c, const float* __restrict__ intr,
    float* __restrict__ cull, float* __restrict__ recs)
{
    __shared__ float zall[NG];
    __shared__ int   partial[4][64];

    const int tid = threadIdx.x;
    const int b   = blockIdx.x;
    const float t = tptr[0];
    const float R00=w2c[0], R01=w2c[1], R02=w2c[2],  tx=w2c[3];
    const float R10=w2c[4], R11=w2c[5], R12=w2c[6],  ty=w2c[7];
    const float R20=w2c[8], R21=w2c[9], R22=w2c[10], tz=w2c[11];
    const float fx=intr[0], cx=intr[2], fy=intr[4], cy=intr[5];

    // ---- step 1: all-gaussian zc into LDS ----
    #pragma unroll
    for (int k = 0; k < 4; ++k) {
        const int g = tid + k*256;
        const float dt = t - times[g];
        const float mx = fmaf(dt, vels[g*3+0], means[g*3+0]);
        const float my = fmaf(dt, vels[g*3+1], means[g*3+1]);
        const float mz = fmaf(dt, vels[g*3+2], means[g*3+2]);
        zall[g] = R20*mx + R21*my + R22*mz + tz;
    }
    __syncthreads();

    // ---- step 2 ----
    float o_u=0, o_v=0, o_rx=0, o_ry=0, o_hA=0, o_B=0, o_hC=0, o_smax=0;
    float o_op=0, o_cr=0, o_cg=0, o_cb=0;
    if (tid < 64) {
        // heavy pre for gaussian g = b*64 + tid (registers only)
        const int g = b*64 + tid;
        const float dt = t - times[g];
        const float mx = fmaf(dt, vels[g*3+0], means[g*3+0]);
        const float my = fmaf(dt, vels[g*3+1], means[g*3+1]);
        const float mz = fmaf(dt, vels[g*3+2], means[g*3+2]);

        const float o = opacs[g];
        const float sig_o = 1.f / (1.f + __expf(-o));
        const float ratio = dt * __expf(-durs[g]);
        const float opac = sig_o * __expf(-0.5f * ratio * ratio);

        const float xc = R00*mx + R01*my + R02*mz + tx;
        const float yc = R10*mx + R11*my + R12*mz + ty;
        const float zc = R20*mx + R21*my + R22*mz + tz;
        const float iz = 1.f / zc;
        const float u = fx*xc*iz + cx;
        const float v = fy*yc*iz + cy;

        float qw=quats[g*4+0], qx=quats[g*4+1], qy=quats[g*4+2], qz=quats[g*4+3];
        const float qn = rsqrtf(qw*qw + qx*qx + qy*qy + qz*qz);
        qw*=qn; qx*=qn; qy*=qn; qz*=qn;
        const float sx = __expf(scales[g*3+0]);
        const float sy = __expf(scales[g*3+1]);
        const float sz = __expf(scales[g*3+2]);
        const float G00 = 1.f-2.f*(qy*qy+qz*qz), G01 = 2.f*(qx*qy-qw*qz), G02 = 2.f*(qx*qz+qw*qy);
        const float G10 = 2.f*(qx*qy+qw*qz), G11 = 1.f-2.f*(qx*qx+qz*qz), G12 = 2.f*(qy*qz-qw*qx);
        const float G20 = 2.f*(qx*qz-qw*qy), G21 = 2.f*(qy*qz+qw*qx), G22 = 1.f-2.f*(qx*qx+qy*qy);
        const float M00=G00*sx, M01=G01*sy, M02=G02*sz;
        const float M10=G10*sx, M11=G11*sy, M12=G12*sz;
        const float M20=G20*sx, M21=G21*sy, M22=G22*sz;
        const float W00=R00*M00+R01*M10+R02*M20, W01=R00*M01+R01*M11+R02*M21, W02=R00*M02+R01*M12+R02*M22;
        const float W10=R10*M00+R11*M10+R12*M20, W11=R10*M01+R11*M11+R12*M21, W12=R10*M02+R11*M12+R12*M22;
        const float W20=R20*M00+R21*M10+R22*M20, W21=R20*M01+R21*M11+R22*M21, W22=R20*M02+R21*M12+R22*M22;
        const float xdz = xc*iz, ydz = yc*iz;
        const float fxiz = fx*iz, fyiz = fy*iz;
        const float T00 = fxiz*(W00 - xdz*W20), T01 = fxiz*(W01 - xdz*W21), T02 = fxiz*(W02 - xdz*W22);
        const float T10 = fyiz*(W10 - ydz*W20), T11 = fyiz*(W11 - ydz*W21), T12 = fyiz*(W12 - ydz*W22);
        const float a = T00*T00 + T01*T01 + T02*T02 + 0.3f;
        const float bb = T00*T10 + T01*T11 + T02*T12;
        const float c = T10*T10 + T11*T11 + T12*T12 + 0.3f;
        const float det = a*c - bb*bb;
        const float idet = 1.f / det;
        const float conA = c*idet, conB = -bb*idet, conC = a*idet;

        const bool valid = (zc > 0.01f) && (det > 1e-12f);
        const float op_eff = valid ? opac : 0.f;
        const float smax = (op_eff * 255.f > 0.f) ? (logf(op_eff * 255.f) + 1e-4f) : -1e30f;
        float rx, ry;
        if (smax > 0.f) {
            rx = sqrtf(2.f * smax * a) + 0.01f;
            ry = sqrtf(2.f * smax * c) + 0.01f;
        } else {
            rx = -1e30f; ry = -1e30f;
        }

        const float cpx = -(R00*tx + R10*ty + R20*tz);
        const float cpy = -(R01*tx + R11*ty + R21*tz);
        const float cpz = -(R02*tx + R12*ty + R22*tz);
        float dx0 = mx-cpx, dy0 = my-cpy, dz0 = mz-cpz;
        const float dn = rsqrtf(dx0*dx0 + dy0*dy0 + dz0*dz0);
        const float X = dx0*dn, Y = dy0*dn, Z = dz0*dn;
        const float XX=X*X, YY=Y*Y, ZZ=Z*Z;

        float bs[16];
        bs[0]  = 0.28209479177387814f;
        bs[1]  = -0.4886025119029199f * Y;
        bs[2]  =  0.4886025119029199f * Z;
        bs[3]  = -0.4886025119029199f * X;
        bs[4]  =  1.0925484305920792f * X * Y;
        bs[5]  = -1.0925484305920792f * Y * Z;
        bs[6]  =  0.31539156525252005f * (2.f*ZZ - XX - YY);
        bs[7]  = -1.0925484305920792f * X * Z;
        bs[8]  =  0.5462742152960396f * (XX - YY);
        bs[9]  = -0.5900435899266435f * Y * (3.f*XX - YY);
        bs[10] =  2.890611442640554f  * X * Y * Z;
        bs[11] = -0.4570457994644658f * Y * (4.f*ZZ - XX - YY);
        bs[12] =  0.3731763325901154f * Z * (2.f*ZZ - 3.f*XX - 3.f*YY);
        bs[13] = -0.4570457994644658f * X * (4.f*ZZ - XX - YY);
        bs[14] =  1.445305721320277f  * Z * (XX - YY);
        bs[15] = -0.5900435899266435f * X * (XX - 3.f*YY);

        float cr = 0.5f, cg = 0.5f, cb = 0.5f;
        cr = fmaf(bs[0], sh0[g*3+0], cr);
        cg = fmaf(bs[0], sh0[g*3+1], cg);
        cb = fmaf(bs[0], sh0[g*3+2], cb);
        #pragma unroll
        for (int k = 1; k < 16; ++k) {
            const float* s = shn + g*45 + (k-1)*3;
            cr = fmaf(bs[k], s[0], cr);
            cg = fmaf(bs[k], s[1], cg);
            cb = fmaf(bs[k], s[2], cb);
        }
        cr = fmaxf(cr, 0.f); cg = fmaxf(cg, 0.f); cb = fmaxf(cb, 0.f);

        o_u = u; o_v = v; o_rx = rx; o_ry = ry;
        o_hA = 0.5f*conA; o_B = conB; o_hC = 0.5f*conC; o_smax = smax;
        o_op = op_eff; o_cr = cr; o_cg = cg; o_cb = cb;
    } else {
        // waves 1-3: quarter partial ranks for the block's 64 gaussians.
        // wave 1 -> quarters 0 and 3; wave 2 -> 1; wave 3 -> 2.
        const int wv = tid >> 6;         // 1..3
        const int lane = tid & 63;
        const int tg = b*64 + lane;      // gaussian this lane ranks
        const float zt = zall[tg];
        const float4* __restrict__ z4 = (const float4*)zall;
        #pragma unroll
        for (int pass = 0; pass < 2; ++pass) {
            if (pass == 1 && wv != 1) break;
            const int q = (pass == 0) ? (wv - 1) : 3;
            int cnt = 0;
            #pragma unroll 4
            for (int j4 = q*64; j4 < q*64 + 64; ++j4) {
                const float4 z = z4[j4];
                const int j = j4*4;
                cnt += (z.x < zt) || (z.x == zt && (j+0) < tg);
                cnt += (z.y < zt) || (z.y == zt && (j+1) < tg);
                cnt += (z.z < zt) || (z.z == zt && (j+2) < tg);
                cnt += (z.w < zt) || (z.w == zt && (j+3) < tg);
            }
            partial[q][lane] = cnt;
        }
    }
    __syncthreads();

    // ---- step 3: scatter by stable global rank ----
    if (tid < 64) {
        const int r = partial[0][tid] + partial[1][tid] + partial[2][tid] + partial[3][tid];
        float4* c4 = (float4*)cull;
        float4* r4 = (float4*)recs;
        c4[r]     = make_float4(o_u, o_v, o_rx, o_ry);
        r4[2*r]   = make_float4(o_hA, o_B, o_hC, o_smax);
        r4[2*r+1] = make_float4(o_op, o_cr, o_cg, o_cb);
    }
}

// ---------------- Kernel 2: rasterize + composite (depth-sorted input) ----------------
// Block = 256 thr = 4 waves; 64-px row strip; wave = one 256-deep chunk.
// Phase 0: coalesced float4 cull loads -> 4 hit masks (rec0 kept in regs).
// Phase 1: per 64-chunk, hit lanes gather rec1/rec2 into LDS at prefix-popcount
//          slots (<=64, exact); composite in bit order with 1-deep prefetch.
__global__ __launch_bounds__(256) void k_raster(
    const float* __restrict__ cull, const float* __restrict__ recs,
    float* __restrict__ out)
{
    __shared__ float4 hrec[4][64][3];
    __shared__ float4 part[4][64];
    const int lane = threadIdx.x & 63;
    const int wv   = threadIdx.x >> 6;
    const int pix  = blockIdx.x * 64 + lane;
    const float px = (float)(pix & (IW-1)) + 0.5f;
    const float py = (float)(pix >> 8) + 0.5f;
    const float px0  = (float)((blockIdx.x & 3) << 6) + 0.5f;
    const float px63 = px0 + 63.f;

    const float4* __restrict__ c4 = (const float4*)cull;
    const float4* __restrict__ r4 = (const float4*)recs;
    const int base = wv * 256;

    // ---- phase 0: cull (coalesced), keep rec0 in regs ----
    float4 r0s[4];
    unsigned long long masks[4];
    #pragma unroll
    for (int k = 0; k < 4; ++k) {
        const float4 r0 = c4[base + k*64 + lane];
        r0s[k] = r0;
        masks[k] = __ballot((fabsf(py - r0.y) <= r0.w) &&
                            (r0.x + r0.z >= px0) && (r0.x - r0.z <= px63));
    }

    // ---- phase 1: gather + composite per 64-chunk ----
    float T = 1.f, cr = 0.f, cg = 0.f, cb = 0.f;
    #pragma unroll
    for (int k = 0; k < 4; ++k) {
        const unsigned long long m = masks[k];
        if (!m) continue;                      // wave-uniform branch
        if ((m >> lane) & 1ull) {
            const int pos = (int)__popcll(m & ((1ull << lane) - 1ull));
            const int g = base + k*64 + lane;
            hrec[wv][pos][0] = r0s[k];
            hrec[wv][pos][1] = r4[g*2+0];
            hrec[wv][pos][2] = r4[g*2+1];
        }
        asm volatile("s_waitcnt lgkmcnt(0)" ::: "memory");
        __builtin_amdgcn_sched_barrier(0);
        const int cnt = (int)__popcll(m);
        float4 ra = hrec[wv][0][0];
        float4 rb = hrec[wv][0][1];
        float4 rc = hrec[wv][0][2];
        for (int i = 0; i < cnt; ++i) {
            float4 na, nb, nc;
            if (i + 1 < cnt) {
                na = hrec[wv][i+1][0];
                nb = hrec[wv][i+1][1];
                nc = hrec[wv][i+1][2];
            }
            const float dx = px - ra.x;
            const float dy = py - ra.y;
            const float sigma = fmaf(dx, fmaf(rb.x, dx, rb.y*dy), rb.z*dy*dy);
            if (sigma >= 0.f && sigma <= rb.w) {
                const float al = fminf(0.999f, rc.x * __expf(-sigma));
                if (al >= (1.f/255.f)) {
                    const float w = al * T;
                    cr = fmaf(w, rc.y, cr);
                    cg = fmaf(w, rc.z, cg);
                    cb = fmaf(w, rc.w, cb);
                    T -= w;
                }
            }
            ra = na; rb = nb; rc = nc;
        }
    }

    part[wv][lane] = make_float4(cr, cg, cb, T);
    __syncthreads();
    if (threadIdx.x < 64) {
        const float4 v0 = part[0][lane];
        const float4 v1 = part[1][lane];
        const float4 v2 = part[2][lane];
        const float4 v3 = part[3][lane];
        float r = v0.x, g2 = v0.y, b2 = v0.z, Tt = v0.w;
        r = fmaf(Tt, v1.x, r); g2 = fmaf(Tt, v1.y, g2); b2 = fmaf(Tt, v1.z, b2); Tt *= v1.w;
        r = fmaf(Tt, v2.x, r); g2 = fmaf(Tt, v2.y, g2); b2 = fmaf(Tt, v2.z, b2); Tt *= v2.w;
        r = fmaf(Tt, v3.x, r); g2 = fmaf(Tt, v3.y, g2); b2 = fmaf(Tt, v3.z, b2); Tt *= v3.w;
        const int p3 = pix * 3;
        out[p3+0] = fminf(fmaxf(r,  0.f), 1.f);
        out[p3+1] = fminf(fmaxf(g2, 0.f), 1.f);
        out[p3+2] = fminf(fmaxf(b2, 0.f), 1.f);
        out[NPIX*3 + pix] = 1.f - Tt;
    }
}

extern "C" void kernel_launch(void* const* d_in, const int* in_sizes, int n_in,
                              void* d_out, int out_size, void* d_ws, size_t ws_size,
                              hipStream_t stream) {
    const float* means  = (const float*)d_in[0];
    const float* scales = (const float*)d_in[1];
    const float* quats  = (const float*)d_in[2];
    const float* opacs  = (const float*)d_in[3];
    const float* sh0    = (const float*)d_in[4];
    const float* shn    = (const float*)d_in[5];
    const float* times  = (const float*)d_in[6];
    const float* durs   = (const float*)d_in[7];
    const float* vels   = (const float*)d_in[8];
    const float* tptr   = (const float*)d_in[9];
    const float* w2c    = (const float*)d_in[10];
    const float* intr   = (const float*)d_in[11];

    float* ws   = (float*)d_ws;
    float* cull = ws;              // 1024*4 floats  (sorted)
    float* recs = ws + 4*NG;       // 1024*8 floats  (sorted)

    hipLaunchKernelGGL(k_pre, dim3(16), dim3(256), 0, stream,
                       means, scales, quats, opacs, sh0, shn,
                       times, durs, vels, tptr, w2c, intr, cull, recs);
    hipLaunchKernelGGL(k_raster, dim3(NPIX/64), dim3(256), 0, stream,
                       cull, recs, (float*)d_out);
}

// Round 6
// 19.305 us; speedup vs baseline: 1.2740x; 1.2740x over previous
//
#include <hip/hip_runtime.h>
#include <math.h>

#define NG 1024
#define IH 256
#define IW 256
#define NPIX (IH*IW)

// unsorted record (12 floats / gaussian), produced by k_pre:
//   raw[g*12+ 0.. 3] = (u, v, rx, ry)
//   raw[g*12+ 4.. 7] = (0.5*conA, conB, 0.5*conC, smax)
//   raw[g*12+ 8..11] = (op, cr, cg, cb)
// sorted layout, produced by k_rank (split for coalesced cull reads):
//   cull[r]   = float4 (u, v, rx, ry)
//   recs[2r]  = float4 (0.5*conA, conB, 0.5*conC, smax)
//   recs[2r+1]= float4 (op, cr, cg, cb)

// ---------------- Kernel 1: per-Gaussian preprocessing ----------------
__global__ __launch_bounds__(64) void k_pre(
    const float* __restrict__ means, const float* __restrict__ scales,
    const float* __restrict__ quats, const float* __restrict__ opacs,
    const float* __restrict__ sh0, const float* __restrict__ shn,
    const float* __restrict__ times, const float* __restrict__ durs,
    const float* __restrict__ vels, const float* __restrict__ tptr,
    const float* __restrict__ w2c, const float* __restrict__ intr,
    float* __restrict__ zc_out, float* __restrict__ raw)
{
    int g = blockIdx.x * 64 + threadIdx.x;
    if (g >= NG) return;
    const float t = tptr[0];
    const float R00=w2c[0], R01=w2c[1], R02=w2c[2],  tx=w2c[3];
    const float R10=w2c[4], R11=w2c[5], R12=w2c[6],  ty=w2c[7];
    const float R20=w2c[8], R21=w2c[9], R22=w2c[10], tz=w2c[11];
    const float fx=intr[0], cx=intr[2], fy=intr[4], cy=intr[5];

    const float dt = t - times[g];
    const float mx = fmaf(dt, vels[g*3+0], means[g*3+0]);
    const float my = fmaf(dt, vels[g*3+1], means[g*3+1]);
    const float mz = fmaf(dt, vels[g*3+2], means[g*3+2]);

    const float o = opacs[g];
    const float sig_o = 1.f / (1.f + __expf(-o));
    const float ratio = dt * __expf(-durs[g]);
    const float opac = sig_o * __expf(-0.5f * ratio * ratio);

    const float xc = R00*mx + R01*my + R02*mz + tx;
    const float yc = R10*mx + R11*my + R12*mz + ty;
    const float zc = R20*mx + R21*my + R22*mz + tz;
    const float iz = 1.f / zc;
    const float u = fx*xc*iz + cx;
    const float v = fy*yc*iz + cy;

    float qw=quats[g*4+0], qx=quats[g*4+1], qy=quats[g*4+2], qz=quats[g*4+3];
    const float qn = rsqrtf(qw*qw + qx*qx + qy*qy + qz*qz);
    qw*=qn; qx*=qn; qy*=qn; qz*=qn;
    const float sx = __expf(scales[g*3+0]);
    const float sy = __expf(scales[g*3+1]);
    const float sz = __expf(scales[g*3+2]);
    const float G00 = 1.f-2.f*(qy*qy+qz*qz), G01 = 2.f*(qx*qy-qw*qz), G02 = 2.f*(qx*qz+qw*qy);
    const float G10 = 2.f*(qx*qy+qw*qz), G11 = 1.f-2.f*(qx*qx+qz*qz), G12 = 2.f*(qy*qz-qw*qx);
    const float G20 = 2.f*(qx*qz-qw*qy), G21 = 2.f*(qy*qz+qw*qx), G22 = 1.f-2.f*(qx*qx+qy*qy);
    const float M00=G00*sx, M01=G01*sy, M02=G02*sz;
    const float M10=G10*sx, M11=G11*sy, M12=G12*sz;
    const float M20=G20*sx, M21=G21*sy, M22=G22*sz;
    const float W00=R00*M00+R01*M10+R02*M20, W01=R00*M01+R01*M11+R02*M21, W02=R00*M02+R01*M12+R02*M22;
    const float W10=R10*M00+R11*M10+R12*M20, W11=R10*M01+R11*M11+R12*M21, W12=R10*M02+R11*M12+R12*M22;
    const float W20=R20*M00+R21*M10+R22*M20, W21=R20*M01+R21*M11+R22*M21, W22=R20*M02+R21*M12+R22*M22;
    const float xdz = xc*iz, ydz = yc*iz;
    const float fxiz = fx*iz, fyiz = fy*iz;
    const float T00 = fxiz*(W00 - xdz*W20), T01 = fxiz*(W01 - xdz*W21), T02 = fxiz*(W02 - xdz*W22);
    const float T10 = fyiz*(W10 - ydz*W20), T11 = fyiz*(W11 - ydz*W21), T12 = fyiz*(W12 - ydz*W22);
    const float a = T00*T00 + T01*T01 + T02*T02 + 0.3f;
    const float b = T00*T10 + T01*T11 + T02*T12;
    const float c = T10*T10 + T11*T11 + T12*T12 + 0.3f;
    const float det = a*c - b*b;
    const float idet = 1.f / det;
    const float conA = c*idet, conB = -b*idet, conC = a*idet;

    const bool valid = (zc > 0.01f) && (det > 1e-12f);
    const float op_eff = valid ? opac : 0.f;
    const float smax = (op_eff * 255.f > 0.f) ? (logf(op_eff * 255.f) + 1e-4f) : -1e30f;
    float rx, ry;
    if (smax > 0.f) {
        rx = sqrtf(2.f * smax * a) + 0.01f;
        ry = sqrtf(2.f * smax * c) + 0.01f;
    } else {
        rx = -1e30f; ry = -1e30f;
    }

    const float cpx = -(R00*tx + R10*ty + R20*tz);
    const float cpy = -(R01*tx + R11*ty + R21*tz);
    const float cpz = -(R02*tx + R12*ty + R22*tz);
    float dx0 = mx-cpx, dy0 = my-cpy, dz0 = mz-cpz;
    const float dn = rsqrtf(dx0*dx0 + dy0*dy0 + dz0*dz0);
    const float X = dx0*dn, Y = dy0*dn, Z = dz0*dn;
    const float XX=X*X, YY=Y*Y, ZZ=Z*Z;

    float bs[16];
    bs[0]  = 0.28209479177387814f;
    bs[1]  = -0.4886025119029199f * Y;
    bs[2]  =  0.4886025119029199f * Z;
    bs[3]  = -0.4886025119029199f * X;
    bs[4]  =  1.0925484305920792f * X * Y;
    bs[5]  = -1.0925484305920792f * Y * Z;
    bs[6]  =  0.31539156525252005f * (2.f*ZZ - XX - YY);
    bs[7]  = -1.0925484305920792f * X * Z;
    bs[8]  =  0.5462742152960396f * (XX - YY);
    bs[9]  = -0.5900435899266435f * Y * (3.f*XX - YY);
    bs[10] =  2.890611442640554f  * X * Y * Z;
    bs[11] = -0.4570457994644658f * Y * (4.f*ZZ - XX - YY);
    bs[12] =  0.3731763325901154f * Z * (2.f*ZZ - 3.f*XX - 3.f*YY);
    bs[13] = -0.4570457994644658f * X * (4.f*ZZ - XX - YY);
    bs[14] =  1.445305721320277f  * Z * (XX - YY);
    bs[15] = -0.5900435899266435f * X * (XX - 3.f*YY);

    float cr = 0.5f, cg = 0.5f, cb = 0.5f;
    cr = fmaf(bs[0], sh0[g*3+0], cr);
    cg = fmaf(bs[0], sh0[g*3+1], cg);
    cb = fmaf(bs[0], sh0[g*3+2], cb);
    #pragma unroll
    for (int k = 1; k < 16; ++k) {
        const float* s = shn + g*45 + (k-1)*3;
        cr = fmaf(bs[k], s[0], cr);
        cg = fmaf(bs[k], s[1], cg);
        cb = fmaf(bs[k], s[2], cb);
    }
    cr = fmaxf(cr, 0.f); cg = fmaxf(cg, 0.f); cb = fmaxf(cb, 0.f);

    zc_out[g] = zc;
    float* r = raw + g*12;
    r[0] = u;         r[1] = v;    r[2]  = rx;        r[3]  = ry;
    r[4] = 0.5f*conA; r[5] = conB; r[6]  = 0.5f*conC; r[7]  = smax;
    r[8] = op_eff;    r[9] = cr;   r[10] = cg;        r[11] = cb;
}

// ---------------- Kernel 2: stable depth rank + scatter (split layout) ----------------
__global__ __launch_bounds__(64) void k_rank(
    const float* __restrict__ zc, const float* __restrict__ raw,
    float* __restrict__ cull, float* __restrict__ recs)
{
    const int g = blockIdx.x;
    const int lane = threadIdx.x;
    const float myz = zc[g];
    int cnt = 0;
    #pragma unroll
    for (int k = 0; k < 16; ++k) {
        const int j = k*64 + lane;
        const float z = zc[j];
        const bool lt = (z < myz) || (z == myz && j < g);
        cnt += (int)__popcll(__ballot(lt));
    }
    // cnt is wave-uniform = stable ascending rank of g
    if (lane < 4)       cull[cnt*4 + lane]       = raw[g*12 + lane];
    else if (lane < 12) recs[cnt*8 + (lane - 4)] = raw[g*12 + lane];
}

// ---------------- Kernel 3: rasterize + composite (R3 structure) ----------------
// Block = 256 thr = 4 waves; 64-px row strip; wave = one 256-deep chunk.
// Phase 0: coalesced float4 cull loads (dense array) -> 4 hit masks; rec0 in regs.
// Phase 1: per 64-chunk, hit lanes gather rec1/rec2 into LDS at prefix-popcount
//          slots; all lanes composite from LDS broadcast reads in bit order.
__global__ __launch_bounds__(256) void k_raster(
    const float* __restrict__ cull, const float* __restrict__ recs,
    float* __restrict__ out)
{
    __shared__ float4 hrec[4][64][3];
    __shared__ float4 part[4][64];
    const int lane = threadIdx.x & 63;
    const int wv   = threadIdx.x >> 6;
    const int pix  = blockIdx.x * 64 + lane;
    const float px = (float)(pix & (IW-1)) + 0.5f;
    const float py = (float)(pix >> 8) + 0.5f;
    const float px0  = (float)((blockIdx.x & 3) << 6) + 0.5f;
    const float px63 = px0 + 63.f;

    const float4* __restrict__ c4 = (const float4*)cull;
    const float4* __restrict__ r4 = (const float4*)recs;
    const int base = wv * 256;

    // ---- phase 0: cull (coalesced dense), keep rec0 in regs ----
    float4 r0s[4];
    unsigned long long masks[4];
    #pragma unroll
    for (int k = 0; k < 4; ++k) {
        const float4 r0 = c4[base + k*64 + lane];
        r0s[k] = r0;
        masks[k] = __ballot((fabsf(py - r0.y) <= r0.w) &&
                            (r0.x + r0.z >= px0) && (r0.x - r0.z <= px63));
    }

    // ---- phase 1: gather + composite per 64-chunk ----
    float T = 1.f, cr = 0.f, cg = 0.f, cb = 0.f;
    #pragma unroll
    for (int k = 0; k < 4; ++k) {
        const unsigned long long m = masks[k];
        if (!m) continue;                      // wave-uniform branch
        if ((m >> lane) & 1ull) {
            const int pos = (int)__popcll(m & ((1ull << lane) - 1ull));
            const int g = base + k*64 + lane;
            hrec[wv][pos][0] = r0s[k];
            hrec[wv][pos][1] = r4[g*2+0];
            hrec[wv][pos][2] = r4[g*2+1];
        }
        asm volatile("s_waitcnt lgkmcnt(0)" ::: "memory");
        const int cnt = (int)__popcll(m);
        for (int i = 0; i < cnt; ++i) {
            const float4 ra = hrec[wv][i][0];  // u, v, rx, ry
            const float4 rb = hrec[wv][i][1];  // 0.5A, B, 0.5C, smax
            const float4 rc = hrec[wv][i][2];  // op, cr, cg, cb
            const float dx = px - ra.x;
            const float dy = py - ra.y;
            const float sigma = fmaf(dx, fmaf(rb.x, dx, rb.y*dy), rb.z*dy*dy);
            if (sigma >= 0.f && sigma <= rb.w) {
                const float al = fminf(0.999f, rc.x * __expf(-sigma));
                if (al >= (1.f/255.f)) {
                    const float w = al * T;
                    cr = fmaf(w, rc.y, cr);
                    cg = fmaf(w, rc.z, cg);
                    cb = fmaf(w, rc.w, cb);
                    T -= w;
                }
            }
        }
    }

    part[wv][lane] = make_float4(cr, cg, cb, T);
    __syncthreads();
    if (threadIdx.x < 64) {
        const float4 v0 = part[0][lane];
        const float4 v1 = part[1][lane];
        const float4 v2 = part[2][lane];
        const float4 v3 = part[3][lane];
        float r = v0.x, g2 = v0.y, b2 = v0.z, Tt = v0.w;
        r = fmaf(Tt, v1.x, r); g2 = fmaf(Tt, v1.y, g2); b2 = fmaf(Tt, v1.z, b2); Tt *= v1.w;
        r = fmaf(Tt, v2.x, r); g2 = fmaf(Tt, v2.y, g2); b2 = fmaf(Tt, v2.z, b2); Tt *= v2.w;
        r = fmaf(Tt, v3.x, r); g2 = fmaf(Tt, v3.y, g2); b2 = fmaf(Tt, v3.z, b2); Tt *= v3.w;
        const int p3 = pix * 3;
        out[p3+0] = fminf(fmaxf(r,  0.f), 1.f);
        out[p3+1] = fminf(fmaxf(g2, 0.f), 1.f);
        out[p3+2] = fminf(fmaxf(b2, 0.f), 1.f);
        out[NPIX*3 + pix] = 1.f - Tt;
    }
}

extern "C" void kernel_launch(void* const* d_in, const int* in_sizes, int n_in,
                              void* d_out, int out_size, void* d_ws, size_t ws_size,
                              hipStream_t stream) {
    const float* means  = (const float*)d_in[0];
    const float* scales = (const float*)d_in[1];
    const float* quats  = (const float*)d_in[2];
    const float* opacs  = (const float*)d_in[3];
    const float* sh0    = (const float*)d_in[4];
    const float* shn    = (const float*)d_in[5];
    const float* times  = (const float*)d_in[6];
    const float* durs   = (const float*)d_in[7];
    const float* vels   = (const float*)d_in[8];
    const float* tptr   = (const float*)d_in[9];
    const float* w2c    = (const float*)d_in[10];
    const float* intr   = (const float*)d_in[11];

    float* ws   = (float*)d_ws;
    float* zc   = ws;                      // 1024 floats
    float* raw  = ws + 1024;               // 1024*12 floats (unsorted)
    float* cull = ws + 1024 + 12*NG;       // 1024*4 floats  (sorted, dense)
    float* recs = ws + 1024 + 16*NG;       // 1024*8 floats  (sorted)

    hipLaunchKernelGGL(k_pre, dim3(16), dim3(64), 0, stream,
                       means, scales, quats, opacs, sh0, shn,
                       times, durs, vels, tptr, w2c, intr, zc, raw);
    hipLaunchKernelGGL(k_rank, dim3(NG), dim3(64), 0, stream, zc, raw, cull, recs);
    hipLaunchKernelGGL(k_raster, dim3(NPIX/64), dim3(256), 0, stream,
                       cull, recs, (float*)d_out);
}